// Round 4
// baseline (117.530 us; speedup 1.0000x reference)
//
#include <hip/hip_runtime.h>

// Single-level deformable attention.
// value: (bs=16, K=2500, H=8, D=32) f32
// sampling_locations: (bs, Q=2000, H=8, L=1, P=4, 2) f32
// attention_weights:  (bs, Q, H, 1, P) f32
// out: (bs, Q, H*D=256) f32
//
// R1-R5: global-gather path capped at 42us = 524MB/42us = 12.5 TB/s L3 BW.
// R6: LDS stage, 8-way ch split: 74.5us (staging 16B/k over-fetched 4x;
//     1024 blocks > 256 CU so cg-siblings not co-resident -> no L2 dedupe).
// R7: ch HALVES (64B/k), 256 blocks = 256 CU (siblings co-resident),
//     1024 thr, LDS 160,000B: ~39us (dur_us 115.6 - 77 overhead).
//     Remaining gap vs 17us pipe model: exposed LDS latency. R6 showed
//     VGPR=52 for a 16-wide gather -> compiler serialized reads ~3 deep
//     (same disease as R4's global loads).
// R8: force 16-deep LDS pipelining with an empty-asm keeper on v[0..15]
//     (R5's trick, applied to ds_read); rotate loc/attw prefetch one pass
//     ahead (clamped, uniform control flow); peel pass-0 addr math above
//     the barrier; pass loop unroll 1 to keep one v[16] live (VGPR<128).

#define FH 50
#define FW 50
#define KK (FH * FW)   // 2500
#define NH 8
#define ND 32
#define NQ 2000
#define NP 4
#define TPB 1024
#define QSLOTS (TPB / 4)               // 256 queries per pass
#define NPASS 8

typedef float f32x4 __attribute__((ext_vector_type(4)));

__global__ __launch_bounds__(TPB, 4) void deform_attn_kernel(
    const float* __restrict__ value,
    const float* __restrict__ loc,
    const float* __restrict__ attw,
    float* __restrict__ out)
{
    // blockIdx = half*128 + b*8 + h  (=> blockIdx % 8 == h: both halves of
    // a (b,h) land on the same XCD; 256 blocks = 256 CUs, all co-resident)
    const int id = blockIdx.x;
    const int half = id >> 7;        // channel half: ch 0-15 or 16-31
    const int bh = id & 127;
    const int b  = bh >> 3;
    const int h  = bh & 7;

    __shared__ f32x4 lds[KK * 4];    // 160,000 B: [k][quad], 64B per k

    const int t = threadIdx.x;
    const int quad = t & 3;          // which f32x4 of this 16-ch half
    const int qi = t >> 2;           // query slot 0..255

    const f32x4* __restrict__ lp = (const f32x4*)loc;
    const f32x4* __restrict__ ap = (const f32x4*)attw;

    // ---- prefetch pass-0 loc/attw (overlaps with staging) ----
    const int gid0 = (b * NQ + qi) * NH + h;
    f32x4 nl0 = lp[(size_t)gid0 * 2 + 0];
    f32x4 nl1 = lp[(size_t)gid0 * 2 + 1];
    f32x4 na  = ap[gid0];

    // ---- stage value[b, k, h, half*16 .. half*16+15] -> lds[k*4+q] ----
    {
        const f32x4* __restrict__ src =
            (const f32x4*)value + (size_t)b * KK * 64 + h * 8 + half * 4;
#pragma unroll
        for (int i = 0; i < 10; ++i) {           // 10*1024 >= 10000
            const int j = i * TPB + t;           // k*4 + q
            if (j < KK * 4)
                lds[j] = src[(size_t)(j >> 2) * 64 + (j & 3)];
        }
    }

    int   idx[16];
    float wts[16];

    auto computeOW = [&](const f32x4 l0, const f32x4 l1, const f32x4 a4) {
        const float pxx[NP] = {l0.x, l0.z, l1.x, l1.z};
        const float pyy[NP] = {l0.y, l0.w, l1.y, l1.w};
        const float awp[NP] = {a4.x, a4.y, a4.z, a4.w};
#pragma unroll
        for (int p = 0; p < NP; ++p) {
            const float fx = pxx[p] * (float)FW - 0.5f;
            const float fy = pyy[p] * (float)FH - 0.5f;
            const float x0f = floorf(fx);
            const float y0f = floorf(fy);
            const int x0 = (int)x0f, y0 = (int)y0f;
            const int x1 = x0 + 1, y1 = y0 + 1;
            const float wx1 = fx - x0f, wx0 = 1.f - wx1;
            const float wy1 = fy - y0f, wy0 = 1.f - wy1;

            const bool vx0 = (x0 >= 0) & (x0 < FW);
            const bool vx1 = (x1 >= 0) & (x1 < FW);
            const bool vy0 = (y0 >= 0) & (y0 < FH);
            const bool vy1 = (y1 >= 0) & (y1 < FH);

            const int cx0 = min(max(x0, 0), FW - 1);
            const int cx1 = min(max(x1, 0), FW - 1);
            const int cy0 = min(max(y0, 0), FH - 1);
            const int cy1 = min(max(y1, 0), FH - 1);

            idx[p * 4 + 0] = cy0 * FW + cx0;
            idx[p * 4 + 1] = cy0 * FW + cx1;
            idx[p * 4 + 2] = cy1 * FW + cx0;
            idx[p * 4 + 3] = cy1 * FW + cx1;

            wts[p * 4 + 0] = ((vx0 & vy0) ? (wx0 * wy0) : 0.f) * awp[p];
            wts[p * 4 + 1] = ((vx1 & vy0) ? (wx1 * wy0) : 0.f) * awp[p];
            wts[p * 4 + 2] = ((vx0 & vy1) ? (wx0 * wy1) : 0.f) * awp[p];
            wts[p * 4 + 3] = ((vx1 & vy1) ? (wx1 * wy1) : 0.f) * awp[p];
        }
    };

    // ---- pass-0 addr math above the barrier; issue pass-1 prefetch ----
    {
        const f32x4 cl0 = nl0, cl1 = nl1, ca = na;
        const int qn = qi + QSLOTS;                 // < 512, always valid
        const int gidn = (b * NQ + qn) * NH + h;
        nl0 = lp[(size_t)gidn * 2 + 0];
        nl1 = lp[(size_t)gidn * 2 + 1];
        na  = ap[gidn];
        computeOW(cl0, cl1, ca);
    }

    __syncthreads();

    f32x4* __restrict__ op = (f32x4*)out;

#pragma unroll 1
    for (int pass = 0; pass < NPASS; ++pass) {
        const int qq = pass * QSLOTS + qi;

        // ---- gather: 16 ds_read_b128 forced simultaneously live ----
        if (qq < NQ) {
            f32x4 v[16];
#pragma unroll
            for (int i = 0; i < 16; ++i)
                v[i] = lds[idx[i] * 4 + quad];
            asm volatile("" ::
                "v"(v[0]), "v"(v[1]), "v"(v[2]), "v"(v[3]),
                "v"(v[4]), "v"(v[5]), "v"(v[6]), "v"(v[7]),
                "v"(v[8]), "v"(v[9]), "v"(v[10]), "v"(v[11]),
                "v"(v[12]), "v"(v[13]), "v"(v[14]), "v"(v[15]));
            f32x4 acc = {0.f, 0.f, 0.f, 0.f};
#pragma unroll
            for (int i = 0; i < 16; ++i) {
                acc.x += wts[i] * v[i].x;
                acc.y += wts[i] * v[i].y;
                acc.z += wts[i] * v[i].z;
                acc.w += wts[i] * v[i].w;
            }
            op[(size_t)(b * NQ + qq) * 64 + h * 8 + half * 4 + quad] = acc;
        }

        // ---- rotate: consume prefetched loc, issue pass+2, addr math ----
        if (pass < NPASS - 1) {
            const f32x4 cl0 = nl0, cl1 = nl1, ca = na;
            const int qn = min(qq + 2 * QSLOTS, NQ - 1);   // clamped, uniform
            const int gidn = (b * NQ + qn) * NH + h;
            nl0 = lp[(size_t)gidn * 2 + 0];
            nl1 = lp[(size_t)gidn * 2 + 1];
            na  = ap[gidn];
            computeOW(cl0, cl1, ca);
        }
    }
}

extern "C" void kernel_launch(void* const* d_in, const int* in_sizes, int n_in,
                              void* d_out, int out_size, void* d_ws, size_t ws_size,
                              hipStream_t stream) {
    const float* value = (const float*)d_in[0];
    // d_in[1] = value_spatial_shapes (int64), ignored: hardcoded 50x50
    const float* loc  = (const float*)d_in[2];
    const float* attw = (const float*)d_in[3];
    float* out = (float*)d_out;

    const int blocks = 2 * 16 * 8;   // half * b * h = 256
    deform_attn_kernel<<<blocks, TPB, 0, stream>>>(value, loc, attw, out);
}